// Round 5
// baseline (260.563 us; speedup 1.0000x reference)
//
#include <hip/hip_runtime.h>
#include <cmath>

#define NUM_CLS 58

typedef float v2f __attribute__((ext_vector_type(2)));

// ---------------- merged prep: binarize w1/w2/w3/w4 + pack w0 interleaved ----------------
// blocks 0..1151 -> w1, 1152..2303 -> w2, 2304..3455 -> w3, 3456..3583 -> w4,
// 3584..3647 -> pack w0 into wsp2[64 pairs][64]: wsp2[p][2k]=w0[2p][k], [2k+1]=w0[2p+1][k]
__global__ void prep_all(const float* __restrict__ w0, const float* __restrict__ w1,
                         const float* __restrict__ w2, const float* __restrict__ w3,
                         const float* __restrict__ w4,
                         unsigned long long* __restrict__ wb1, unsigned long long* __restrict__ wb2,
                         unsigned long long* __restrict__ wb3, unsigned long long* __restrict__ wb4,
                         float* __restrict__ wsp2) {
    int id = blockIdx.x, lane = threadIdx.x;
    if (id < 3456) {
        const float* w = id < 1152 ? w1 : (id < 2304 ? w2 : w3);
        unsigned long long* o = id < 1152 ? wb1 : (id < 2304 ? wb2 : wb3);
        int item = id % 1152;
        int oc = item / 9, k = item % 9;
        const float* base = w + (size_t)oc * 1152 + k;   // element ic at base[ic*9]
        unsigned long long b0 = __ballot(base[lane * 9] >= 0.f);
        unsigned long long b1 = __ballot(base[(lane + 64) * 9] >= 0.f);
        if (lane == 0) { o[item * 2] = b0; o[item * 2 + 1] = b1; }
    } else if (id < 3584) {
        int oc = id - 3456;
        unsigned long long b0 = __ballot(w4[oc * 128 + lane] >= 0.f);
        unsigned long long b1 = __ballot(w4[oc * 128 + lane + 64] >= 0.f);
        if (lane == 0) { wb4[oc * 2] = b0; wb4[oc * 2 + 1] = b1; }
    } else {
        int p = id - 3584;                 // oc pair
        float v = 0.f;
        if (lane < 54) {
            int k = lane >> 1, parity = lane & 1;
            v = w0[(2 * p + parity) * 27 + k];
        }
        wsp2[p * 64 + lane] = v;           // pad 54..63 with zeros
    }
}

// ---- one block per batch element: conv0+pool -> binconv1+pool -> binconv2+pool
//      -> binconv3 -> binconv4 -> relu -> w5 -> softmax ----
__global__ __launch_bounds__(256) void fused_net(
    const float* __restrict__ x, const float* __restrict__ wsp2,
    const unsigned long long* __restrict__ wb1, const unsigned long long* __restrict__ wb2,
    const unsigned long long* __restrict__ wb3, const unsigned long long* __restrict__ wb4,
    const float* __restrict__ w5, float* __restrict__ out) {
    __shared__ unsigned long long bits1[450];  // [15*15][2]
    __shared__ unsigned long long bits2[72];   // [6*6][2]
    __shared__ unsigned long long bits3[18];   // [3*3][2]
    __shared__ unsigned long long bits4[2];
    __shared__ float r_s[128];
    __shared__ float l_s[NUM_CLS];
    __shared__ float e_s[NUM_CLS];

    int b = blockIdx.x;
    int tid = threadIdx.x;

    // ================= phase 0: float conv0 + maxpool2 + sign-pack =================
    if (tid < 225) {                      // thread = pooled pixel
        int py = tid / 15, px = tid % 15;
        const float* xb = x + (size_t)b * 3072;
        float xp[48];                     // 4x4 patch x 3 channels in registers (loaded ONCE)
#pragma unroll
        for (int c = 0; c < 3; c++)
#pragma unroll
            for (int yy = 0; yy < 4; yy++) {
                const float2* rp = (const float2*)(xb + c * 1024 + (2 * py + yy) * 32 + 2 * px);
                float2 a = rp[0];
                float2 q = rp[1];
                xp[c * 16 + yy * 4 + 0] = a.x;
                xp[c * 16 + yy * 4 + 1] = a.y;
                xp[c * 16 + yy * 4 + 2] = q.x;
                xp[c * 16 + yy * 4 + 3] = q.y;
            }
        unsigned long long b0 = 0, b1 = 0, r0 = 0, r1 = 0;
        for (int p = 0; p < 64; p++) {    // oc pair = (2p, 2p+1)
            const v2f* wrow = (const v2f*)(wsp2 + p * 64);   // wave-uniform -> s_load
            v2f a00 = {0.f, 0.f}, a01 = {0.f, 0.f}, a10 = {0.f, 0.f}, a11 = {0.f, 0.f};
#pragma unroll
            for (int c = 0; c < 3; c++)
#pragma unroll
                for (int ky = 0; ky < 3; ky++)
#pragma unroll
                    for (int kx = 0; kx < 3; kx++) {
                        v2f w2 = wrow[c * 9 + ky * 3 + kx];
                        float x00 = xp[c * 16 + ky * 4 + kx];
                        float x01 = xp[c * 16 + ky * 4 + kx + 1];
                        float x10 = xp[c * 16 + (ky + 1) * 4 + kx];
                        float x11 = xp[c * 16 + (ky + 1) * 4 + kx + 1];
                        a00 = __builtin_elementwise_fma((v2f){x00, x00}, w2, a00);
                        a01 = __builtin_elementwise_fma((v2f){x01, x01}, w2, a01);
                        a10 = __builtin_elementwise_fma((v2f){x10, x10}, w2, a10);
                        a11 = __builtin_elementwise_fma((v2f){x11, x11}, w2, a11);
                    }
#pragma unroll
            for (int parity = 0; parity < 2; parity++) {
                float s0 = parity ? a00.y : a00.x;
                float s1 = parity ? a01.y : a01.x;
                float s2 = parity ? a10.y : a10.x;
                float s3 = parity ? a11.y : a11.x;
                bool pos = (s0 >= 0.f) | (s1 >= 0.f) | (s2 >= 0.f) | (s3 >= 0.f);
                bool need = (fabsf(s0) < 1e-4f) | (fabsf(s1) < 1e-4f) |
                            (fabsf(s2) < 1e-4f) | (fabsf(s3) < 1e-4f);
                int oc = 2 * p + parity;
                unsigned long long bit = pos ? 1ull : 0ull;
                unsigned long long nbit = need ? 1ull : 0ull;
                if (oc < 64) { b0 |= bit << oc; r0 |= nbit << oc; }
                else         { b1 |= bit << (oc - 64); r1 |= nbit << (oc - 64); }
            }
        }
        // -------- rare cold path: redo borderline oc's in f64 --------
        if (__builtin_expect((r0 | r1) != 0ull, 0)) {
#pragma unroll
            for (int half = 0; half < 2; half++) {
                unsigned long long r = half ? r1 : r0;
                while (r) {
                    int i = __builtin_ctzll(r);
                    r &= r - 1;
                    int oc = half * 64 + i;
                    const float* wr = wsp2 + (oc >> 1) * 64;   // per-lane (vector) loads, rare
                    int par = oc & 1;
                    bool pos = false;
#pragma unroll
                    for (int dy = 0; dy < 2; dy++)
#pragma unroll
                        for (int dx = 0; dx < 2; dx++) {
                            double sd = 0.0;
#pragma unroll
                            for (int c = 0; c < 3; c++)
#pragma unroll
                                for (int ky = 0; ky < 3; ky++)
#pragma unroll
                                    for (int kx = 0; kx < 3; kx++)
                                        sd += (double)xp[c * 16 + (dy + ky) * 4 + dx + kx] *
                                              (double)wr[2 * (c * 9 + ky * 3 + kx) + par];
                            pos |= (sd >= 0.0);
                        }
                    unsigned long long bit = pos ? 1ull : 0ull;
                    if (half) b1 = (b1 & ~(1ull << i)) | (bit << i);
                    else      b0 = (b0 & ~(1ull << i)) | (bit << i);
                }
            }
        }
        bits1[tid * 2] = b0;
        bits1[tid * 2 + 1] = b1;
    }
    __syncthreads();

    int lane = tid & 63, wave = tid >> 6, half = wave & 1, pair = wave >> 1;
    int oc = half * 64 + lane;

    // ================= phase 1: binconv1 (15->13) + maxpool2 (->6) =================
    {
        unsigned long long wr[18];
#pragma unroll
        for (int j = 0; j < 18; j++) wr[j] = wb1[oc * 18 + j];
        for (int p = pair; p < 36; p += 2) {
            int py = p / 6, px = p % 6;
            unsigned long long xp[4][4][2];
#pragma unroll
            for (int yy = 0; yy < 4; yy++)
#pragma unroll
                for (int xx = 0; xx < 4; xx++) {
                    int idx = ((2 * py + yy) * 15 + (2 * px + xx)) * 2;
                    xp[yy][xx][0] = bits1[idx];
                    xp[yy][xx][1] = bits1[idx + 1];
                }
            bool pos = false;
#pragma unroll
            for (int dy = 0; dy < 2; dy++)
#pragma unroll
                for (int dx = 0; dx < 2; dx++) {
                    int P = 0;
#pragma unroll
                    for (int ky = 0; ky < 3; ky++)
#pragma unroll
                        for (int kx = 0; kx < 3; kx++) {
                            P += __popcll(xp[dy + ky][dx + kx][0] ^ wr[(ky * 3 + kx) * 2]);
                            P += __popcll(xp[dy + ky][dx + kx][1] ^ wr[(ky * 3 + kx) * 2 + 1]);
                        }
                    pos |= (P <= 576);   // 1152 - 2P >= 0
                }
            unsigned long long m = __ballot(pos);
            if (lane == 0) bits2[p * 2 + half] = m;
        }
    }
    __syncthreads();

    // ================= phase 2: binconv2 (6->4) + maxpool(2,s1) (->3) =================
    {
        unsigned long long wr[18];
#pragma unroll
        for (int j = 0; j < 18; j++) wr[j] = wb2[oc * 18 + j];
        for (int p = pair; p < 9; p += 2) {
            int py = p / 3, px = p % 3;
            bool pos = false;
#pragma unroll
            for (int dy = 0; dy < 2; dy++)
#pragma unroll
                for (int dx = 0; dx < 2; dx++) {
                    int P = 0;
#pragma unroll
                    for (int ky = 0; ky < 3; ky++)
#pragma unroll
                        for (int kx = 0; kx < 3; kx++) {
                            int idx = ((py + dy + ky) * 6 + (px + dx + kx)) * 2;
                            P += __popcll(bits2[idx] ^ wr[(ky * 3 + kx) * 2]);
                            P += __popcll(bits2[idx + 1] ^ wr[(ky * 3 + kx) * 2 + 1]);
                        }
                    pos |= (P <= 576);
                }
            unsigned long long m = __ballot(pos);
            if (lane == 0) bits3[p * 2 + half] = m;
        }
    }
    __syncthreads();

    // ================= phase 3: binconv3 + binconv4 + relu + w5 + softmax =================
    if (tid < 128) {
        int P = 0;
#pragma unroll
        for (int k = 0; k < 9; k++) {
            P += __popcll(bits3[k * 2] ^ wb3[tid * 18 + k * 2]);
            P += __popcll(bits3[k * 2 + 1] ^ wb3[tid * 18 + k * 2 + 1]);
        }
        unsigned long long m = __ballot(P <= 576);
        if ((tid & 63) == 0) bits4[tid >> 6] = m;
    }
    __syncthreads();
    if (tid < 128) {
        unsigned long long i0 = bits4[0], i1 = bits4[1];
        int v = 128 - 2 * (int)(__popcll(i0 ^ wb4[tid * 2]) + __popcll(i1 ^ wb4[tid * 2 + 1]));
        r_s[tid] = v > 0 ? (float)v : 0.f;   // relu
    }
    __syncthreads();
    if (tid < NUM_CLS) {
        float l = 0.f;
#pragma unroll 8
        for (int k = 0; k < 128; k++) l = fmaf(w5[tid * 128 + k], r_s[k], l);
        l_s[tid] = l;
    }
    __syncthreads();
    if (tid < NUM_CLS) {
        float mx = -1e30f;
        for (int k = 0; k < NUM_CLS; k++) mx = fmaxf(mx, l_s[k]);
        e_s[tid] = expf(l_s[tid] - mx);
    }
    __syncthreads();
    if (tid < NUM_CLS) {
        float sum = 0.f;
        for (int k = 0; k < NUM_CLS; k++) sum += e_s[k];
        out[(size_t)b * NUM_CLS + tid] = e_s[tid] / sum;
    }
}

extern "C" void kernel_launch(void* const* d_in, const int* in_sizes, int n_in,
                              void* d_out, int out_size, void* d_ws, size_t ws_size,
                              hipStream_t stream) {
    const float* x  = (const float*)d_in[0];
    const float* w0 = (const float*)d_in[1];
    const float* w1 = (const float*)d_in[2];
    const float* w2 = (const float*)d_in[3];
    const float* w3 = (const float*)d_in[4];
    const float* w4 = (const float*)d_in[5];
    const float* w5 = (const float*)d_in[6];
    float* out = (float*)d_out;

    int B = in_sizes[0] / 3072;   // 1024

    size_t off = 0;
    auto carve = [&](size_t bytes) {
        void* p = (char*)d_ws + off;
        off += (bytes + 255) & ~(size_t)255;
        return p;
    };
    unsigned long long* wb1 = (unsigned long long*)carve(1152 * 2 * 8);
    unsigned long long* wb2 = (unsigned long long*)carve(1152 * 2 * 8);
    unsigned long long* wb3 = (unsigned long long*)carve(1152 * 2 * 8);
    unsigned long long* wb4 = (unsigned long long*)carve(128 * 2 * 8);
    float* wsp2 = (float*)carve(64 * 64 * 4);   // interleaved padded w0
    (void)ws_size; (void)n_in; (void)out_size;

    prep_all<<<3648, 64, 0, stream>>>(w0, w1, w2, w3, w4, wb1, wb2, wb3, wb4, wsp2);
    fused_net<<<B, 256, 0, stream>>>(x, wsp2, wb1, wb2, wb3, wb4, w5, out);
}